// Round 4
// baseline (279.940 us; speedup 1.0000x reference)
//
#include <hip/hip_runtime.h>
#include <cstddef>

// ============================================================================
// VLSTM via bf16 MFMA, R8: MT=128, GRID=256 (=#CUs, single round).
//  - R7 analysis: step = F (fixed: barrier drain, post-barrier oproj tail,
//    phase stalls, ~2.5-5k cyc) + V (MFMA 3.3k + VALU 6.1k). 2 rounds pay
//    40F; 1 round with 2x work pays 20F. MT 64->128, 20 steps total.
//  - acc in 2 row-tile slots (32 VGPR): GEMM(rt)->slot rt&1, ACT(rt) frees.
//  - W_out frags in LDS (-16 VGPR); bias added in ACT, MFMA C=0 (-16 VGPR).
//  - out-proj(t-1) folded into compute phase: reads Ar (=h(t-1), stable),
//    mask from regs (Mp), direct global store (contiguous 320B/wave).
//    NOTHING runs post-barrier -> step is one phase + barrier.
//  - Keeps: A dbuf 1 barrier/step, reg-resident gate weights, ballot mask,
//    prescaled activations (log2-domain c), h state in regs.
// ============================================================================

typedef __attribute__((ext_vector_type(8))) short  s16x8;   // 8 x bf16
typedef __attribute__((ext_vector_type(4))) float  f32x4;

namespace {
constexpr int T_STEPS = 20;
constexpr int NN      = 32768;
constexpr int D_EMB   = 64;
constexpr int D_H     = 128;
constexpr int D_OUT   = 5;
constexpr int G4      = 512;
constexpr int MT      = 128;                  // nodes per block (was 64)
constexpr int BLOCK   = 512;
constexpr int GRID    = NN / MT;              // 256 blocks = 256 CUs
constexpr int RT_N    = MT / 16;              // 8 row-tiles
constexpr int WP_ELEMS   = 8 * 4 * 6 * 64 * 8;
constexpr int WOUT_ELEMS = 4 * 64 * 8;
constexpr int A_ELEMS    = RT_N * 6 * 64 * 8;   // 24576 shorts = 48 KB / buf
constexpr float LOG2E = 1.4426950408889634f;
constexpr float AM4   = -4.0f * LOG2E;
constexpr float AP2   =  2.0f * LOG2E;
constexpr float CINV  = 0.34657359027997264f;   // 1/(2*log2e)
constexpr size_t OFF_H = (size_t)T_STEPS * NN * D_OUT;
constexpr size_t OFF_C = OFF_H + (size_t)NN * D_H;
}

__device__ __forceinline__ unsigned short f2bf(float x) {
    unsigned u = __float_as_uint(x);
    u = (u + 0x7FFFu + ((u >> 16) & 1u)) >> 16;     // RNE
    return (unsigned short)u;
}
__device__ __forceinline__ unsigned short f2bf_hw(float x) {
    __bf16 b = (__bf16)x;
    union { __bf16 b; unsigned short u; } cv;
    cv.b = b;
    return cv.u;
}
__device__ __forceinline__ float bf2f(unsigned short h) {
    return __uint_as_float(((unsigned)h) << 16);
}
__device__ __forceinline__ float exp2f_fast(float x) {
#if __has_builtin(__builtin_amdgcn_exp2f)
    return __builtin_amdgcn_exp2f(x);
#else
    return __expf(x * 0.6931471805599453f);
#endif
}
__device__ __forceinline__ float sig_pre(float a) {   // sigmoid, a = -x*log2e
    return __builtin_amdgcn_rcpf(1.0f + exp2f_fast(a));
}

// ----------------------------------------------------------------------------
__global__ void prepack_kernel(const float* __restrict__ W_ih,
                               const float* __restrict__ b_ih,
                               const float* __restrict__ W_hh,
                               const float* __restrict__ b_hh,
                               const float* __restrict__ W_out,
                               unsigned short* __restrict__ Wp,
                               unsigned short* __restrict__ WoutF,
                               float* __restrict__ b_sum) {
    int idx = blockIdx.x * blockDim.x + threadIdx.x;
    if (idx < WP_ELEMS) {
        int j    = idx & 7;
        int L    = (idx >> 3) & 63;
        int rest = idx >> 9;
        int kb   = rest % 6;
        int gw   = rest / 6;
        int g    = gw & 3, w = gw >> 2;
        int k    = kb * 32 + (L >> 4) * 8 + j;
        int col  = g * D_H + w * 16 + (L & 15);
        float v  = (k < D_EMB) ? W_ih[k * G4 + col] : W_hh[(k - D_EMB) * G4 + col];
        float s  = (g == 2) ? (2.0f * LOG2E) : (-LOG2E);
        Wp[idx] = f2bf(v * s);
    } else if (idx < WP_ELEMS + WOUT_ELEMS) {
        int i2 = idx - WP_ELEMS;
        int j = i2 & 7, L = (i2 >> 3) & 63, kb2 = i2 >> 9;
        int k = kb2 * 32 + (L >> 4) * 8 + j;
        int n = L & 15;
        WoutF[i2] = (n < D_OUT) ? f2bf(W_out[k * D_OUT + n]) : (unsigned short)0;
    }
    if (idx < G4) {
        int g = idx / D_H;
        float s = (g == 2) ? (2.0f * LOG2E) : (-LOG2E);
        b_sum[idx] = (b_ih[idx] + b_hh[idx]) * s;
    }
}

// ----------------------------------------------------------------------------
__global__ __launch_bounds__(BLOCK, 2) void vlstm_kernel(
    const float* __restrict__ nodes,   // [T][N][2]
    const int*   __restrict__ mask,    // [T][N]
    const float* __restrict__ h0,      // [N][128]
    const float* __restrict__ c0,      // [N][128]
    const float* __restrict__ W_embed, // [2][64]
    const float* __restrict__ b_embed, // [64]
    const float* __restrict__ b_out,   // [5]
    const unsigned short* __restrict__ Wp,
    const unsigned short* __restrict__ WoutF,
    const float* __restrict__ b_sum,
    float* __restrict__ out)
{
    __shared__ __align__(16) unsigned short A[2][A_ELEMS];   // 96 KB dbuf
    __shared__ __align__(16) unsigned short WoS[WOUT_ELEMS]; // 4 KB
    __shared__ float We_s[2 * D_EMB];
    __shared__ float be_s[D_EMB];
    __shared__ __align__(16) unsigned long long msk64[2][2];

    const int tid  = threadIdx.x;
    const int wave = tid >> 6;
    const int L    = tid & 63;
    const int quad = L >> 4;
    const int l15  = L & 15;
    const int n_base = blockIdx.x * MT;

    // ---- gate weights -> registers, once (96 VGPR/wave) ----
    const unsigned short* wbase = Wp + (size_t)wave * (4 * 6 * 64 * 8);
    s16x8 Bf[4][6];
    #pragma unroll
    for (int g = 0; g < 4; g++)
        #pragma unroll
        for (int kb = 0; kb < 6; kb++)
            Bf[g][kb] = *(const s16x8*)(wbase + ((g * 6 + kb) * 64 + L) * 8);

    const int u_lane = wave * 16 + l15;
    float bias[4];
    #pragma unroll
    for (int g = 0; g < 4; g++) bias[g] = b_sum[g * D_H + u_lane];
    const float bo = (l15 < D_OUT) ? b_out[l15] : 0.0f;

    // per-thread A h-row write geometry
    const int kb_u = 2 + (u_lane >> 5);
    const int fl   = ((u_lane >> 3) & 3) * 16 + quad * 4;
    const int j_u  = u_lane & 7;

    // ---- one-time LDS staging ----
    for (int i = tid; i < 3 * D_EMB; i += BLOCK) {
        if (i < 2 * D_EMB) We_s[i] = W_embed[i];
        else               be_s[i - 2 * D_EMB] = b_embed[i - 2 * D_EMB];
    }
    for (int i = tid; i < WOUT_ELEMS; i += BLOCK) WoS[i] = WoutF[i];

    // ---- h, c -> registers (c as cL = 2c*log2e); h -> A[0] h-rows ----
    float          cL[RT_N][4];
    unsigned short hr[RT_N][4];
    #pragma unroll
    for (int rt = 0; rt < RT_N; rt++)
        #pragma unroll
        for (int r = 0; r < 4; r++) {
            int m = rt * 16 + quad * 4 + r;
            cL[rt][r] = AP2 * c0[(size_t)(n_base + m) * D_H + u_lane];
            hr[rt][r] = f2bf_hw(h0[(size_t)(n_base + m) * D_H + u_lane]);
            A[0][((rt * 6 + kb_u) * 64 + fl + r) * 8 + j_u] = hr[rt][r];
        }

    // ---- emb mapping: 4 threads/node, 16 emb dims each (2 x b128) ----
    const int node_e = tid >> 2;
    const int eb2    = tid & 3;
    int idx_e[2];
    #pragma unroll
    for (int s = 0; s < 2; s++) {
        int e0 = eb2 * 16 + s * 8;
        idx_e[s] = (((node_e >> 4) * 6 + (e0 >> 5)) * 64 +
                    ((e0 >> 3) & 3) * 16 + (node_e & 15)) * 8;
    }

#define EMB_WRITE(AW, XV) do {                                                 \
    _Pragma("unroll")                                                          \
    for (int s = 0; s < 2; s++) {                                              \
        s16x8 ev;                                                              \
        _Pragma("unroll")                                                      \
        for (int j = 0; j < 8; j++) {                                          \
            int e = eb2 * 16 + s * 8 + j;                                      \
            float v = fmaf((XV).x, We_s[e], fmaf((XV).y, We_s[D_EMB + e], be_s[e])); \
            ev[j] = (short)f2bf_hw(fmaxf(v, 0.0f));                            \
        }                                                                      \
        *(s16x8*)((AW) + idx_e[s]) = ev;                                       \
    } } while (0)

    // ---- emb(0) + mask(0) -> A[0] ----
    {
        float2 x0 = *(const float2*)(nodes + (size_t)(n_base + node_e) * 2);
        EMB_WRITE(A[0], x0);
        int lm0 = (tid < MT) ? mask[n_base + tid] : 0;
        if (wave < 2) {
            unsigned long long bm = __ballot(lm0 != 0);
            if (L == 0) msk64[0][wave] = bm;
        }
    }
    __syncthreads();   // prologue barrier

// GEMM of one row-tile into acc slot rt&1; MFMA C=0 inline on kb=0
#define GEMM_RT(rt) do {                                                       \
    {   s16x8 af0 = *(const s16x8*)(Ar + (((rt) * 6 + 0) * 64 + L) * 8);       \
        _Pragma("unroll")                                                      \
        for (int g = 0; g < 4; g++)                                            \
            acc[(rt) & 1][g] = __builtin_amdgcn_mfma_f32_16x16x32_bf16(        \
                af0, Bf[g][0], (f32x4){0.f, 0.f, 0.f, 0.f}, 0, 0, 0); }        \
    _Pragma("unroll")                                                          \
    for (int kb = 1; kb < 6; kb++) {                                           \
        s16x8 af = *(const s16x8*)(Ar + (((rt) * 6 + kb) * 64 + L) * 8);       \
        _Pragma("unroll")                                                      \
        for (int g = 0; g < 4; g++)                                            \
            acc[(rt) & 1][g] = __builtin_amdgcn_mfma_f32_16x16x32_bf16(        \
                af, Bf[g][kb], acc[(rt) & 1][g], 0, 0, 0); }                   \
} while (0)

// Activations + state update + unconditional h-write (slot rt&1 freed after)
#define ACT_RT(rt, MW) do {                                                    \
    unsigned nib = (unsigned)((MW) >> (((rt) & 3) * 16 + quad * 4)) & 0xFu;    \
    _Pragma("unroll")                                                          \
    for (int r = 0; r < 4; r++) {                                              \
        float gi = sig_pre(acc[(rt) & 1][0][r] + bias[0]);                     \
        float gf = sig_pre(acc[(rt) & 1][1][r] + bias[1]);                     \
        float rg = sig_pre(acc[(rt) & 1][2][r] + bias[2]);                     \
        float go = sig_pre(acc[(rt) & 1][3][r] + bias[3]);                     \
        float ggL = fmaf(AM4, rg, AP2);            /* 2*log2e*tanh(g) */       \
        float cnL = fmaf(gf, cL[rt][r], gi * ggL); /* 2*log2e*c_new   */       \
        float rr  = __builtin_amdgcn_rcpf(1.0f + exp2f_fast(cnL));             \
        float hv  = go * fmaf(-2.0f, rr, 1.0f);    /* o*tanh(c_new)   */       \
        unsigned short hb = f2bf_hw(hv);                                       \
        if ((nib >> r) & 1u) { cL[rt][r] = cnL; hr[rt][r] = hb; }              \
        Aw[(((rt) * 6 + kb_u) * 64 + fl + r) * 8 + j_u] = hr[rt][r];           \
    } } while (0)

// out-proj for time TIDX from buffer ARP (h rows), mask words MPA/MPB (regs),
// direct masked global store: wave covers contiguous 320B.
#define OPROJ(ARP, TIDX, MPA, MPB) do {                                        \
    f32x4 ao = (f32x4){0.f, 0.f, 0.f, 0.f};                                    \
    _Pragma("unroll")                                                          \
    for (int kb2 = 0; kb2 < 4; kb2++) {                                        \
        s16x8 af = *(const s16x8*)((ARP) + ((wave * 6 + 2 + kb2) * 64 + L) * 8); \
        s16x8 wf = *(const s16x8*)(WoS + (kb2 * 64 + L) * 8);                  \
        ao = __builtin_amdgcn_mfma_f32_16x16x32_bf16(af, wf, ao, 0, 0, 0);     \
    }                                                                          \
    if (l15 < D_OUT) {                                                         \
        unsigned long long Mw = (wave < 4) ? (MPA) : (MPB);                    \
        unsigned nib = (unsigned)(Mw >> ((wave & 3) * 16 + quad * 4)) & 0xFu;  \
        float* ob = out + ((size_t)(TIDX) * NN + n_base) * D_OUT + l15;        \
        _Pragma("unroll")                                                      \
        for (int r = 0; r < 4; r++) {                                          \
            int node = wave * 16 + quad * 4 + r;                               \
            ob[node * D_OUT] = ((nib >> r) & 1u) ? (ao[r] + bo) : 0.0f;        \
        }                                                                      \
    } } while (0)

    unsigned long long Mp0 = 0, Mp1 = 0;

    for (int t = 0; t < T_STEPS; t++) {
        unsigned short* __restrict__ Ar = A[t & 1];
        unsigned short* __restrict__ Aw = A[(t + 1) & 1];

        const unsigned long long M0 = msk64[t & 1][0];
        const unsigned long long M1 = msk64[t & 1][1];

        // prefetch x(t+1)/mask(t+1): consumed late
        float2 xv = make_float2(0.0f, 0.0f);
        int    lm = 0;
        if (t + 1 < T_STEPS) {
            xv = *(const float2*)(nodes + ((size_t)(t + 1) * NN + n_base + node_e) * 2);
            if (tid < MT) lm = mask[(size_t)(t + 1) * NN + n_base + tid];
        }

        f32x4 acc[2][4];
        GEMM_RT(0);
        GEMM_RT(1);
        ACT_RT(0, M0);
        GEMM_RT(2);
        ACT_RT(1, M0);
        GEMM_RT(3);
        ACT_RT(2, M0);
        if (t > 0) OPROJ(Ar, t - 1, Mp0, Mp1);
        ACT_RT(3, M0);
        GEMM_RT(4);
        GEMM_RT(5);
        ACT_RT(4, M1);
        GEMM_RT(6);
        ACT_RT(5, M1);
        GEMM_RT(7);
        ACT_RT(6, M1);
        if (t + 1 < T_STEPS) {
            EMB_WRITE(Aw, xv);
            if (wave < 2) {
                unsigned long long bm = __ballot(lm != 0);
                if (L == 0) msk64[(t + 1) & 1][wave] = bm;
            }
        }
        ACT_RT(7, M1);

        Mp0 = M0; Mp1 = M1;
        __syncthreads();   // THE barrier: nothing runs after it this step
    }

    // ---- epilogue: A[0] holds h(19); Mp = M(19) ----
    OPROJ(A[0], T_STEPS - 1, Mp0, Mp1);

    // h_fin: coalesced from A[0]
    for (int i = tid; i < MT * D_H; i += BLOCK) {
        int node = i >> 7, u = i & 127;
        int idx = (((node >> 4) * 6 + 2 + (u >> 5)) * 64 +
                   ((u >> 3) & 3) * 16 + (node & 15)) * 8 + (u & 7);
        out[OFF_H + (size_t)(n_base + node) * D_H + u] = bf2f(A[0][idx]);
    }

    // c_fin: LDS staging (stride 129), coalesced copy
    __syncthreads();                    // all A reads done
    float* cs = (float*)A;              // 128*129*4 = 66 KB of the 96 KB
    #pragma unroll
    for (int rt = 0; rt < RT_N; rt++)
        #pragma unroll
        for (int r = 0; r < 4; r++) {
            int m = rt * 16 + quad * 4 + r;
            cs[m * 129 + u_lane] = CINV * cL[rt][r];
        }
    __syncthreads();
    for (int i = tid; i < MT * D_H; i += BLOCK) {
        int node = i >> 7, u = i & 127;
        out[OFF_C + (size_t)(n_base + node) * D_H + u] = cs[node * 129 + u];
    }

#undef EMB_WRITE
#undef GEMM_RT
#undef ACT_RT
#undef OPROJ
}

extern "C" void kernel_launch(void* const* d_in, const int* in_sizes, int n_in,
                              void* d_out, int out_size, void* d_ws, size_t ws_size,
                              hipStream_t stream) {
    const float* nodes   = (const float*)d_in[0];
    const int*   mask    = (const int*)  d_in[1];
    const float* h0      = (const float*)d_in[2];
    const float* c0      = (const float*)d_in[3];
    const float* W_embed = (const float*)d_in[4];
    const float* b_embed = (const float*)d_in[5];
    const float* W_ih    = (const float*)d_in[6];
    const float* b_ih    = (const float*)d_in[7];
    const float* W_hh    = (const float*)d_in[8];
    const float* b_hh    = (const float*)d_in[9];
    const float* W_out   = (const float*)d_in[10];
    const float* b_out   = (const float*)d_in[11];
    float* out = (float*)d_out;

    unsigned short* Wp    = (unsigned short*)d_ws;
    unsigned short* WoutF = Wp + WP_ELEMS;
    float*          b_sum = (float*)(WoutF + WOUT_ELEMS);

    prepack_kernel<<<(WP_ELEMS + WOUT_ELEMS + 255) / 256, 256, 0, stream>>>(
        W_ih, b_ih, W_hh, b_hh, W_out, Wp, WoutF, b_sum);

    vlstm_kernel<<<GRID, BLOCK, 0, stream>>>(
        nodes, mask, h0, c0, W_embed, b_embed, b_out, Wp, WoutF, b_sum, out);
}